// Round 3
// baseline (8371.856 us; speedup 1.0000x reference)
//
#include <hip/hip_runtime.h>
#include <hip/hip_bf16.h>

#define V 50257
#define E 768
#define NH 12
#define NL 4
#define SS 1024
#define BB 2
#define FEE 4
#define HD 64
#define EPSL 1e-5f

// ---------------- embed + pos ----------------
__global__ __launch_bounds__(256) void embed_kernel(const int* __restrict__ x, const float* __restrict__ eW,
                                                    const float* __restrict__ pos, float* __restrict__ h){
  size_t i = (size_t)blockIdx.x*256 + threadIdx.x;
  if (i >= (size_t)BB*SS*E) return;
  int e = (int)(i % E);
  size_t bs = i / E;
  int s = (int)(bs % SS);
  int tok = x[bs];
  h[i] = eW[(size_t)tok*E + e] + pos[(size_t)s*E + e];
}

// ---------------- fused attention: one block per (b, head, q-row) ----------------
__global__ __launch_bounds__(256) void attn_kernel(const float* __restrict__ h, float* __restrict__ o){
  int bid = blockIdx.x;                 // b*NH*SS + hh*SS + q
  int q  = bid & (SS-1);
  int hh = (bid >> 10) % NH;
  int b  = bid / (SS*NH);
  const float* base = h + ((size_t)b*SS)*E + hh*HD;
  __shared__ float qv[HD];
  __shared__ float ev[SS];
  __shared__ float sred[4];
  __shared__ float pacc[256];
  int tid = threadIdx.x;
  if (tid < HD) qv[tid] = base[(size_t)q*E + tid];
  __syncthreads();
  int n = q + 1;
  float lmax = -1e30f;
  for (int k = tid; k < n; k += 256){
    const float* kr = base + (size_t)k*E;
    float d = 0.f;
    #pragma unroll
    for (int dd = 0; dd < HD; ++dd) d += qv[dd]*kr[dd];
    d *= 0.125f;                       // 1/sqrt(64)
    ev[k] = d;
    lmax = fmaxf(lmax, d);
  }
  for (int off = 32; off > 0; off >>= 1) lmax = fmaxf(lmax, __shfl_down(lmax, off, 64));
  int wid = tid >> 6, lane = tid & 63;
  if (lane == 0) sred[wid] = lmax;
  __syncthreads();
  if (tid == 0) sred[0] = fmaxf(fmaxf(sred[0], sred[1]), fmaxf(sred[2], sred[3]));
  __syncthreads();
  float mx = sred[0];
  __syncthreads();
  float ls = 0.f;
  for (int k = tid; k < n; k += 256){ float p = __expf(ev[k]-mx); ev[k] = p; ls += p; }
  for (int off = 32; off > 0; off >>= 1) ls += __shfl_down(ls, off, 64);
  if (lane == 0) sred[wid] = ls;
  __syncthreads();
  if (tid == 0) sred[0] = sred[0]+sred[1]+sred[2]+sred[3];
  __syncthreads();
  float inv = 1.0f / sred[0];
  int d = tid & 63, chunk = tid >> 6;
  float acc = 0.f;
  for (int k = chunk; k < n; k += 4) acc += ev[k] * base[(size_t)k*E + d];
  pacc[tid] = acc;
  __syncthreads();
  if (tid < 64){
    float r = (pacc[tid] + pacc[tid+64] + pacc[tid+128] + pacc[tid+192]) * inv;
    o[((size_t)b*SS + q)*E + hh*HD + tid] = r;
  }
}

// ---------------- seq-mean of h ----------------
__global__ __launch_bounds__(256) void hmean_kernel(const float* __restrict__ h, float* __restrict__ hm){
  int idx = blockIdx.x*256 + threadIdx.x;
  if (idx >= BB*E) return;
  int b = idx / E, e = idx % E;
  float s = 0.f;
  for (int t = 0; t < SS; ++t) s += h[((size_t)b*SS + t)*E + e];
  hm[idx] = s * (1.0f/SS);
}

// ---------------- gate = sigmoid(hm @ gW + gb) ----------------
__global__ __launch_bounds__(256) void gate_kernel(const float* __restrict__ hm, const float* __restrict__ gW,
                                                   const float* __restrict__ gb, float* __restrict__ gv){
  int idx = blockIdx.x*256 + threadIdx.x;
  if (idx >= BB*E) return;
  int b = idx / E, nn = idx % E;
  float acc = 0.f;
  for (int k = 0; k < E; ++k) acc += hm[b*E + k] * gW[(size_t)k*E + nn];
  acc += gb[nn];
  gv[idx] = 1.0f / (1.0f + __expf(-acc));
}

// ---------------- GEMM: C[M,N] = A[M,K] @ W[K,N] (+bias) (+gelu), all f32 ----------------
// EPI: 0 = +bias; 1 = +bias + exact gelu; 2 = plain
template<int EPI>
__global__ __launch_bounds__(256) void gemm_kernel(const float* __restrict__ A, const float* __restrict__ W,
                                                   const float* __restrict__ bias, float* __restrict__ C,
                                                   int M, int N, int K){
  __shared__ float As[64][17];
  __shared__ float Wsh[16][68];
  int tid = threadIdx.x;
  int tx = tid & 15, ty = tid >> 4;
  int n0 = blockIdx.x * 64, m0 = blockIdx.y * 64;
  float acc[4][4] = {};
  for (int k0 = 0; k0 < K; k0 += 16){
    #pragma unroll
    for (int l = 0; l < 4; ++l){
      int idx = tid + l*256;
      int r = idx >> 4, c = idx & 15;
      As[r][c] = A[(size_t)(m0 + r)*K + k0 + c];
    }
    #pragma unroll
    for (int l = 0; l < 4; ++l){
      int idx = tid + l*256;
      int r = idx >> 6, c = idx & 63;
      int nn = n0 + c;
      Wsh[r][c] = (nn < N) ? W[(size_t)(k0 + r)*N + nn] : 0.f;
    }
    __syncthreads();
    #pragma unroll
    for (int kk = 0; kk < 16; ++kk){
      float a[4], w[4];
      #pragma unroll
      for (int i = 0; i < 4; ++i) a[i] = As[ty*4 + i][kk];
      #pragma unroll
      for (int j = 0; j < 4; ++j) w[j] = Wsh[kk][tx*4 + j];
      #pragma unroll
      for (int i = 0; i < 4; ++i)
        #pragma unroll
        for (int j = 0; j < 4; ++j) acc[i][j] += a[i]*w[j];
    }
    __syncthreads();
  }
  #pragma unroll
  for (int i = 0; i < 4; ++i){
    int m = m0 + ty*4 + i;
    #pragma unroll
    for (int j = 0; j < 4; ++j){
      int nn = n0 + tx*4 + j;
      if (nn >= N) continue;
      float v = acc[i][j];
      if (EPI == 0 || EPI == 1) v += bias[nn];
      if (EPI == 1) v = 0.5f*v*(1.0f + erff(v*0.70710678f));
      C[(size_t)m*N + nn] = v;
    }
  }
}

// ---------------- residual (+gate) + layernorm ----------------
__global__ __launch_bounds__(256) void ln_kernel(const float* __restrict__ a, const float* __restrict__ resid,
                                                 const float* __restrict__ gatev, const float* __restrict__ g,
                                                 const float* __restrict__ bta, float* __restrict__ out){
  int row = blockIdx.x;       // b*SS + s
  int b = row >> 10;
  int tid = threadIdx.x;
  __shared__ float sred[4];
  float y[3];
  float lsum = 0.f;
  #pragma unroll
  for (int i = 0; i < 3; ++i){
    int e = tid + i*256;
    float v = a[(size_t)row*E + e];
    if (gatev) v *= gatev[b*E + e];
    if (resid) v += resid[(size_t)row*E + e];
    y[i] = v; lsum += v;
  }
  for (int off = 32; off > 0; off >>= 1) lsum += __shfl_down(lsum, off, 64);
  int wid = tid >> 6, lane = tid & 63;
  if (lane == 0) sred[wid] = lsum;
  __syncthreads();
  float mean = (sred[0]+sred[1]+sred[2]+sred[3]) * (1.0f/E);
  __syncthreads();
  float lvar = 0.f;
  #pragma unroll
  for (int i = 0; i < 3; ++i){ float d = y[i]-mean; lvar += d*d; }
  for (int off = 32; off > 0; off >>= 1) lvar += __shfl_down(lvar, off, 64);
  if (lane == 0) sred[wid] = lvar;
  __syncthreads();
  float rstd = rsqrtf((sred[0]+sred[1]+sred[2]+sred[3]) * (1.0f/E) + EPSL);
  __syncthreads();
  #pragma unroll
  for (int i = 0; i < 3; ++i){
    int e = tid + i*256;
    out[(size_t)row*E + e] = (y[i]-mean)*rstd*g[e] + bta[e];
  }
}

extern "C" void kernel_launch(void* const* d_in, const int* in_sizes, int n_in,
                              void* d_out, int out_size, void* d_ws, size_t ws_size,
                              hipStream_t stream) {
  const int*   x      = (const int*)  d_in[0];
  // d_in[1] = causal mask, implemented implicitly
  const float* embedW = (const float*)d_in[2];
  const float* pos    = (const float*)d_in[3];
  const float* fcW    = (const float*)d_in[4];
  const float* fcB    = (const float*)d_in[5];
  const float* gW     = (const float*)d_in[6];
  const float* gB     = (const float*)d_in[7];
  const float* ln1g   = (const float*)d_in[8];
  const float* ln1b   = (const float*)d_in[9];
  const float* ln2g   = (const float*)d_in[10];
  const float* ln2b   = (const float*)d_in[11];
  const float* f1W    = (const float*)d_in[12];
  const float* f1B    = (const float*)d_in[13];
  const float* f2W    = (const float*)d_in[14];
  const float* f2B    = (const float*)d_in[15];
  const float* lnfg   = (const float*)d_in[16];
  const float* lnfb   = (const float*)d_in[17];
  const float* headW  = (const float*)d_in[18];
  float* out = (float*)d_out;

  const size_t BSE = (size_t)BB*SS*E;
  float* h   = (float*)d_ws;
  float* o   = h   + BSE;
  float* tmp = o   + BSE;
  float* f1  = tmp + BSE;
  float* hm  = f1  + BSE*FEE;
  float* gv  = hm  + (size_t)BB*E;

  const int rows = BB*SS;   // 2048

  embed_kernel<<<(int)((BSE + 255)/256), 256, 0, stream>>>(x, embedW, pos, h);

  for (int l = 0; l < NL; ++l){
    size_t oEE = (size_t)l*E*E, oE = (size_t)l*E;
    size_t oF1 = (size_t)l*E*FEE*E, oFb = (size_t)l*FEE*E;

    hmean_kernel<<<(BB*E + 255)/256, 256, 0, stream>>>(h, hm);
    gate_kernel<<<(BB*E + 255)/256, 256, 0, stream>>>(hm, gW + oEE, gB + oE, gv);
    attn_kernel<<<BB*NH*SS, 256, 0, stream>>>(h, o);
    {
      dim3 g1(E/64, rows/64);
      gemm_kernel<0><<<g1, 256, 0, stream>>>(o, fcW + oEE, fcB + oE, tmp, rows, E, E);
    }
    ln_kernel<<<rows, 256, 0, stream>>>(tmp, h, gv, ln1g + oE, ln1b + oE, h);
    {
      dim3 g2((FEE*E)/64, rows/64);
      gemm_kernel<1><<<g2, 256, 0, stream>>>(h, f1W + oF1, f1B + oFb, f1, rows, FEE*E, E);
    }
    {
      dim3 g3(E/64, rows/64);
      gemm_kernel<0><<<g3, 256, 0, stream>>>(f1, f2W + oF1, f2B + oE, tmp, rows, E, FEE*E);
    }
    ln_kernel<<<rows, 256, 0, stream>>>(tmp, h, nullptr, ln2g + oE, ln2b + oE, h);
  }

  ln_kernel<<<rows, 256, 0, stream>>>(h, nullptr, nullptr, lnfg, lnfb, tmp);
  {
    dim3 gh((V + 63)/64, rows/64);
    gemm_kernel<2><<<gh, 256, 0, stream>>>(tmp, headW, nullptr, out, rows, V, E);
  }
}

// Round 4
// 4204.458 us; speedup vs baseline: 1.9912x; 1.9912x over previous
//
#include <hip/hip_runtime.h>
#include <hip/hip_bf16.h>

#define V 50257
#define E 768
#define NH 12
#define NL 4
#define SS 1024
#define BB 2
#define FEE 4
#define HD 64
#define EPSL 1e-5f
#define NPADH 50304   // 393*128, head N padded

typedef __hip_bfloat16 bf16;
typedef __attribute__((ext_vector_type(8))) short short8;
typedef __attribute__((ext_vector_type(4))) float f32x4;

// ---------------- embed + pos ----------------
__global__ __launch_bounds__(256) void embed_kernel(const int* __restrict__ x, const float* __restrict__ eW,
                                                    const float* __restrict__ pos, float* __restrict__ h){
  size_t i = (size_t)blockIdx.x*256 + threadIdx.x;
  if (i >= (size_t)BB*SS*E) return;
  int e = (int)(i % E);
  size_t bs = i / E;
  int s = (int)(bs % SS);
  int tok = x[bs];
  h[i] = eW[(size_t)tok*E + e] + pos[(size_t)s*E + e];
}

// ---------------- fused attention: one block per (b, head, q-row) ----------------
__global__ __launch_bounds__(256) void attn_kernel(const float* __restrict__ h, float* __restrict__ o){
  int bid = blockIdx.x;                 // b*NH*SS + hh*SS + q
  int q  = bid & (SS-1);
  int hh = (bid >> 10) % NH;
  int b  = bid / (SS*NH);
  const float* base = h + ((size_t)b*SS)*E + hh*HD;
  __shared__ float qv[HD];
  __shared__ float ev[SS];
  __shared__ float sred[4];
  __shared__ float pacc[256];
  int tid = threadIdx.x;
  if (tid < HD) qv[tid] = base[(size_t)q*E + tid];
  __syncthreads();
  int n = q + 1;
  float lmax = -1e30f;
  for (int k = tid; k < n; k += 256){
    const float* kr = base + (size_t)k*E;
    float d = 0.f;
    #pragma unroll
    for (int dd = 0; dd < HD; ++dd) d += qv[dd]*kr[dd];
    d *= 0.125f;
    ev[k] = d;
    lmax = fmaxf(lmax, d);
  }
  for (int off = 32; off > 0; off >>= 1) lmax = fmaxf(lmax, __shfl_down(lmax, off, 64));
  int wid = tid >> 6, lane = tid & 63;
  if (lane == 0) sred[wid] = lmax;
  __syncthreads();
  if (tid == 0) sred[0] = fmaxf(fmaxf(sred[0], sred[1]), fmaxf(sred[2], sred[3]));
  __syncthreads();
  float mx = sred[0];
  __syncthreads();
  float ls = 0.f;
  for (int k = tid; k < n; k += 256){ float p = __expf(ev[k]-mx); ev[k] = p; ls += p; }
  for (int off = 32; off > 0; off >>= 1) ls += __shfl_down(ls, off, 64);
  if (lane == 0) sred[wid] = ls;
  __syncthreads();
  if (tid == 0) sred[0] = sred[0]+sred[1]+sred[2]+sred[3];
  __syncthreads();
  float inv = 1.0f / sred[0];
  int d = tid & 63, chunk = tid >> 6;
  float acc = 0.f;
  for (int k = chunk; k < n; k += 4) acc += ev[k] * base[(size_t)k*E + d];
  pacc[tid] = acc;
  __syncthreads();
  if (tid < 64){
    float r = (pacc[tid] + pacc[tid+64] + pacc[tid+128] + pacc[tid+192]) * inv;
    o[((size_t)b*SS + q)*E + hh*HD + tid] = r;
  }
}

// ---------------- seq-mean of h ----------------
__global__ __launch_bounds__(256) void hmean_kernel(const float* __restrict__ h, float* __restrict__ hm){
  int idx = blockIdx.x*256 + threadIdx.x;
  if (idx >= BB*E) return;
  int b = idx / E, e = idx % E;
  float s = 0.f;
  for (int t = 0; t < SS; ++t) s += h[((size_t)b*SS + t)*E + e];
  hm[idx] = s * (1.0f/SS);
}

// ---------------- gate = sigmoid(hm @ gW + gb) ----------------
__global__ __launch_bounds__(256) void gate_kernel(const float* __restrict__ hm, const float* __restrict__ gW,
                                                   const float* __restrict__ gb, float* __restrict__ gv){
  int idx = blockIdx.x*256 + threadIdx.x;
  if (idx >= BB*E) return;
  int b = idx / E, nn = idx % E;
  float acc = 0.f;
  for (int k = 0; k < E; ++k) acc += hm[b*E + k] * gW[(size_t)k*E + nn];
  acc += gb[nn];
  gv[idx] = 1.0f / (1.0f + __expf(-acc));
}

// ---------------- f32 -> bf16 activation convert (n divisible by 4) ----------------
__global__ __launch_bounds__(256) void acvt_kernel(const float* __restrict__ A, bf16* __restrict__ Ab, int n4){
  int i = blockIdx.x*256 + threadIdx.x;
  if (i >= n4) return;
  float4 v = ((const float4*)A)[i];
  size_t b0 = (size_t)i*4;
  Ab[b0+0] = __float2bfloat16(v.x);
  Ab[b0+1] = __float2bfloat16(v.y);
  Ab[b0+2] = __float2bfloat16(v.z);
  Ab[b0+3] = __float2bfloat16(v.w);
}

// ---------------- W[K][N] f32 -> Wt[Npad][K] bf16 (transpose + convert, zero pad) ----------------
__global__ __launch_bounds__(256) void wcvt_kernel(const float* __restrict__ W, bf16* __restrict__ Wt,
                                                   int K, int N, int Npad){
  __shared__ float t[32][33];
  int n0 = blockIdx.x*32, k0 = blockIdx.y*32;
  int tx = threadIdx.x & 31, ty8 = threadIdx.x >> 5;   // 0..7
  #pragma unroll
  for (int i = 0; i < 4; ++i){
    int k = k0 + ty8 + i*8, n = n0 + tx;
    t[ty8 + i*8][tx] = (k < K && n < N) ? W[(size_t)k*N + n] : 0.f;
  }
  __syncthreads();
  #pragma unroll
  for (int i = 0; i < 4; ++i){
    int n = n0 + ty8 + i*8, k = k0 + tx;
    if (n < Npad && k < K) Wt[(size_t)n*K + k] = __float2bfloat16(t[tx][ty8 + i*8]);
  }
}

// ---------------- MFMA GEMM: C[M,N](f32) = A[M,K](bf16) @ Wt[Npad,K]^T (+bias) (+gelu) ----------------
// 128x128 tile, BK=64, 4 waves each owning a 64x64 quadrant, 16x16x32 bf16 MFMA.
// EPI: 0 = +bias; 1 = +bias + exact gelu; 2 = plain
template<int EPI>
__global__ __launch_bounds__(256) void mfma_gemm(const bf16* __restrict__ A, const bf16* __restrict__ Bt,
                                                 const float* __restrict__ bias, float* __restrict__ C,
                                                 int M, int N, int K){
  __shared__ short As[128*64];
  __shared__ short Bs[128*64];
  int tid = threadIdx.x;
  int wave = tid >> 6, lane = tid & 63;
  int wr = wave >> 1, wc = wave & 1;            // 2x2 waves -> 64x64 each
  int m0 = blockIdx.y * 128, n0 = blockIdx.x * 128;
  f32x4 acc[4][4] = {};
  int srow = tid >> 3;                           // 0..31
  int scol = (tid & 7) * 8;                      // 0..56
  const int nks = K >> 6;
  for (int kt = 0; kt < nks; ++kt){
    int kbase = kt * 64;
    __syncthreads();                             // prev-iter LDS reads done
    #pragma unroll
    for (int iss = 0; iss < 4; ++iss){
      int r = srow + iss*32;
      __builtin_amdgcn_global_load_lds(
        (const __attribute__((address_space(1))) void*)(A + (size_t)(m0 + r)*K + kbase + scol),
        (__attribute__((address_space(3))) void*)(As + r*64 + scol), 16, 0, 0);
      __builtin_amdgcn_global_load_lds(
        (const __attribute__((address_space(1))) void*)(Bt + (size_t)(n0 + r)*K + kbase + scol),
        (__attribute__((address_space(3))) void*)(Bs + r*64 + scol), 16, 0, 0);
    }
    __syncthreads();                             // drains vmcnt -> tiles ready
    #pragma unroll
    for (int kk = 0; kk < 2; ++kk){
      short8 af[4], bfr[4];
      int kcol = kk*32 + (lane >> 4)*8;
      #pragma unroll
      for (int m = 0; m < 4; ++m)
        af[m] = *(const short8*)&As[(wr*64 + m*16 + (lane & 15))*64 + kcol];
      #pragma unroll
      for (int n = 0; n < 4; ++n)
        bfr[n] = *(const short8*)&Bs[(wc*64 + n*16 + (lane & 15))*64 + kcol];
      #pragma unroll
      for (int m = 0; m < 4; ++m)
        #pragma unroll
        for (int n = 0; n < 4; ++n)
          acc[m][n] = __builtin_amdgcn_mfma_f32_16x16x32_bf16(af[m], bfr[n], acc[m][n], 0, 0, 0);
    }
  }
  // epilogue: C row = m0+wr*64+m*16+(lane>>4)*4+j, col = n0+wc*64+n*16+(lane&15)  [verified layout]
  int lrow = (lane >> 4)*4, lcol = lane & 15;
  #pragma unroll
  for (int m = 0; m < 4; ++m){
    int row = m0 + wr*64 + m*16 + lrow;
    #pragma unroll
    for (int n = 0; n < 4; ++n){
      int col = n0 + wc*64 + n*16 + lcol;
      if (col >= N) continue;
      float bv = 0.f;
      if (EPI != 2) bv = bias[col];
      #pragma unroll
      for (int j = 0; j < 4; ++j){
        float v = acc[m][n][j] + bv;
        if (EPI == 1) v = 0.5f*v*(1.0f + erff(v*0.70710678f));
        C[(size_t)(row + j)*N + col] = v;
      }
    }
  }
}

// ---------------- residual (+gate) + layernorm ----------------
__global__ __launch_bounds__(256) void ln_kernel(const float* __restrict__ a, const float* __restrict__ resid,
                                                 const float* __restrict__ gatev, const float* __restrict__ g,
                                                 const float* __restrict__ bta, float* __restrict__ out){
  int row = blockIdx.x;
  int b = row >> 10;
  int tid = threadIdx.x;
  __shared__ float sred[4];
  float y[3];
  float lsum = 0.f;
  #pragma unroll
  for (int i = 0; i < 3; ++i){
    int e = tid + i*256;
    float v = a[(size_t)row*E + e];
    if (gatev) v *= gatev[b*E + e];
    if (resid) v += resid[(size_t)row*E + e];
    y[i] = v; lsum += v;
  }
  for (int off = 32; off > 0; off >>= 1) lsum += __shfl_down(lsum, off, 64);
  int wid = tid >> 6, lane = tid & 63;
  if (lane == 0) sred[wid] = lsum;
  __syncthreads();
  float mean = (sred[0]+sred[1]+sred[2]+sred[3]) * (1.0f/E);
  __syncthreads();
  float lvar = 0.f;
  #pragma unroll
  for (int i = 0; i < 3; ++i){ float d = y[i]-mean; lvar += d*d; }
  for (int off = 32; off > 0; off >>= 1) lvar += __shfl_down(lvar, off, 64);
  if (lane == 0) sred[wid] = lvar;
  __syncthreads();
  float rstd = rsqrtf((sred[0]+sred[1]+sred[2]+sred[3]) * (1.0f/E) + EPSL);
  __syncthreads();
  #pragma unroll
  for (int i = 0; i < 3; ++i){
    int e = tid + i*256;
    out[(size_t)row*E + e] = (y[i]-mean)*rstd*g[e] + bta[e];
  }
}

extern "C" void kernel_launch(void* const* d_in, const int* in_sizes, int n_in,
                              void* d_out, int out_size, void* d_ws, size_t ws_size,
                              hipStream_t stream) {
  const int*   x      = (const int*)  d_in[0];
  const float* embedW = (const float*)d_in[2];
  const float* pos    = (const float*)d_in[3];
  const float* fcW    = (const float*)d_in[4];
  const float* fcB    = (const float*)d_in[5];
  const float* gW     = (const float*)d_in[6];
  const float* gB     = (const float*)d_in[7];
  const float* ln1g   = (const float*)d_in[8];
  const float* ln1b   = (const float*)d_in[9];
  const float* ln2g   = (const float*)d_in[10];
  const float* ln2b   = (const float*)d_in[11];
  const float* f1W    = (const float*)d_in[12];
  const float* f1B    = (const float*)d_in[13];
  const float* f2W    = (const float*)d_in[14];
  const float* f2B    = (const float*)d_in[15];
  const float* lnfg   = (const float*)d_in[16];
  const float* lnfb   = (const float*)d_in[17];
  const float* headW  = (const float*)d_in[18];
  float* out = (float*)d_out;

  const size_t BSE = (size_t)BB*SS*E;
  float* h   = (float*)d_ws;
  float* o   = h   + BSE;
  float* tmp = o   + BSE;
  float* f1  = tmp + BSE;
  float* hm  = f1  + BSE*FEE;
  float* gv  = hm  + (size_t)BB*E;
  bf16* Abuf   = (bf16*)(gv + (size_t)BB*E);          // 2048*3072 bf16 max
  bf16* Wbuf   = Abuf + (size_t)2048*3072;            // 3072*768 bf16 max
  bf16* WheadT = Wbuf + (size_t)3072*768;             // NPADH*768 bf16

  const int rows = BB*SS;   // 2048

  embed_kernel<<<(int)((BSE + 255)/256), 256, 0, stream>>>(x, embedW, pos, h);

  // head weight: f32 [E][V] -> bf16 [NPADH][E] once
  {
    dim3 g(NPADH/32, E/32);
    wcvt_kernel<<<g, 256, 0, stream>>>(headW, WheadT, E, V, NPADH);
  }

  for (int l = 0; l < NL; ++l){
    size_t oEE = (size_t)l*E*E, oE = (size_t)l*E;
    size_t oF1 = (size_t)l*E*FEE*E, oFb = (size_t)l*FEE*E;

    hmean_kernel<<<(BB*E + 255)/256, 256, 0, stream>>>(h, hm);
    gate_kernel<<<(BB*E + 255)/256, 256, 0, stream>>>(hm, gW + oEE, gB + oE, gv);
    attn_kernel<<<BB*NH*SS, 256, 0, stream>>>(h, o);

    // fc_out: (2048x768) @ (768x768)
    acvt_kernel<<<(int)(BSE/4 + 255)/256, 256, 0, stream>>>(o, Abuf, (int)(BSE/4));
    { dim3 g(E/32, E/32);  wcvt_kernel<<<g, 256, 0, stream>>>(fcW + oEE, Wbuf, E, E, E); }
    { dim3 g(E/128, rows/128);
      mfma_gemm<0><<<g, 256, 0, stream>>>(Abuf, Wbuf, fcB + oE, tmp, rows, E, E); }

    ln_kernel<<<rows, 256, 0, stream>>>(tmp, h, gv, ln1g + oE, ln1b + oE, h);

    // ff1: (2048x768) @ (768x3072) + gelu
    acvt_kernel<<<(int)(BSE/4 + 255)/256, 256, 0, stream>>>(h, Abuf, (int)(BSE/4));
    { dim3 g((FEE*E)/32, E/32); wcvt_kernel<<<g, 256, 0, stream>>>(f1W + oF1, Wbuf, E, FEE*E, FEE*E); }
    { dim3 g((FEE*E)/128, rows/128);
      mfma_gemm<1><<<g, 256, 0, stream>>>(Abuf, Wbuf, f1B + oFb, f1, rows, FEE*E, E); }

    // ff2: (2048x3072) @ (3072x768)
    acvt_kernel<<<(int)(BSE*FEE/4 + 255)/256, 256, 0, stream>>>(f1, Abuf, (int)(BSE*FEE/4));
    { dim3 g(E/32, (FEE*E)/32); wcvt_kernel<<<g, 256, 0, stream>>>(f2W + oF1, Wbuf, FEE*E, E, E); }
    { dim3 g(E/128, rows/128);
      mfma_gemm<0><<<g, 256, 0, stream>>>(Abuf, Wbuf, f2B + oE, tmp, rows, E, FEE*E); }

    ln_kernel<<<rows, 256, 0, stream>>>(tmp, h, nullptr, ln2g + oE, ln2b + oE, h);
  }

  ln_kernel<<<rows, 256, 0, stream>>>(h, nullptr, nullptr, lnfg, lnfb, tmp);
  acvt_kernel<<<(int)(BSE/4 + 255)/256, 256, 0, stream>>>(tmp, Abuf, (int)(BSE/4));
  {
    dim3 g(NPADH/128, rows/128);
    mfma_gemm<2><<<g, 256, 0, stream>>>(Abuf, WheadT, nullptr, out, rows, V, E);
  }
}

// Round 5
// 1783.006 us; speedup vs baseline: 4.6954x; 2.3581x over previous
//
#include <hip/hip_runtime.h>
#include <hip/hip_bf16.h>

#define V 50257
#define E 768
#define NH 12
#define NL 4
#define SS 1024
#define BB 2
#define FEE 4
#define HD 64
#define EPSL 1e-5f
#define NPADH 50304   // 393*128, head N padded

typedef __hip_bfloat16 bf16;
typedef __attribute__((ext_vector_type(8))) short short8;
typedef __attribute__((ext_vector_type(4))) float f32x4;

#define GLD_SRC(p) (const __attribute__((address_space(1))) void*)(p)
#define GLD_DST(p) (__attribute__((address_space(3))) void*)(p)

// ---------------- embed + pos ----------------
__global__ __launch_bounds__(256) void embed_kernel(const int* __restrict__ x, const float* __restrict__ eW,
                                                    const float* __restrict__ pos, float* __restrict__ h){
  size_t i = (size_t)blockIdx.x*256 + threadIdx.x;
  if (i >= (size_t)BB*SS*E) return;
  int e = (int)(i % E);
  size_t bs = i / E;
  int s = (int)(bs % SS);
  int tok = x[bs];
  h[i] = eW[(size_t)tok*E + e] + pos[(size_t)s*E + e];
}

// ---------------- h(f32) -> hb(bf16, same layout) + vT(bf16, [b][h][d][s]) ----------------
__global__ __launch_bounds__(256) void cvt_attn(const float* __restrict__ h, bf16* __restrict__ hb,
                                                bf16* __restrict__ vT){
  __shared__ float t[64][65];
  int bid = blockIdx.x;
  int st = bid & 15, hh = (bid >> 4) % NH, b = bid / (16*NH);
  int s0 = st*64;
  int c = threadIdx.x & 63, rr = threadIdx.x >> 6;
  #pragma unroll
  for (int i = 0; i < 16; ++i){
    int r = rr*16 + i;
    float v = h[(size_t)(b*SS + s0 + r)*E + hh*HD + c];
    hb[(size_t)(b*SS + s0 + r)*E + hh*HD + c] = __float2bfloat16(v);
    t[r][c] = v;
  }
  __syncthreads();
  #pragma unroll
  for (int i = 0; i < 16; ++i){
    int d = rr*16 + i;
    vT[(size_t)((b*NH + hh)*HD + d)*SS + s0 + c] = __float2bfloat16(t[c][d]);
  }
}

// ---------------- flash MFMA attention ----------------
// block = (b, head, 64-row q tile); 4 waves x 16 q rows. K-tiles of 128.
// Writes softmax(QK^T*scale, causal) @ V directly as bf16 into Ab[2048][768].
__global__ __launch_bounds__(256) void attn_mfma(const bf16* __restrict__ hb, const bf16* __restrict__ vT,
                                                 bf16* __restrict__ Ab){
  __shared__ short Qs[64*64];
  __shared__ short Ks[128*64];
  __shared__ short Vs[64*128];
  __shared__ short Ps[4][16*128];
  int tid = threadIdx.x, wave = tid >> 6, lane = tid & 63;
  int bid = blockIdx.x;
  int qt = bid & 15, hh = (bid >> 4) % NH, b = bid / (16*NH);
  int q0 = qt*64;
  int l15 = lane & 15, l4 = lane >> 4;

  // stage Q tile [64][64]
  #pragma unroll
  for (int rnd = 0; rnd < 2; ++rnd){
    int o = rnd*256 + tid; int row = o >> 3; int cs = (o & 7)*8;
    __builtin_amdgcn_global_load_lds(GLD_SRC(hb + ((size_t)(b*SS + q0 + row)*E + hh*HD + cs)),
                                     GLD_DST(Qs + o*8), 16, 0, 0);
  }

  float mrun[4], lrun[4];
  #pragma unroll
  for (int j = 0; j < 4; ++j){ mrun[j] = -1e30f; lrun[j] = 0.f; }
  f32x4 acco[4] = {};

  int nkt = (qt >> 1) + 1;
  for (int kt = 0; kt < nkt; ++kt){
    int k0 = kt*128;
    __syncthreads();    // prev-iter LDS reads done (also covers Q stage on kt=0)
    #pragma unroll
    for (int rnd = 0; rnd < 4; ++rnd){
      int o = rnd*256 + tid; int row = o >> 3; int cs = (o & 7)*8;
      __builtin_amdgcn_global_load_lds(GLD_SRC(hb + ((size_t)(b*SS + k0 + row)*E + hh*HD + cs)),
                                       GLD_DST(Ks + o*8), 16, 0, 0);
    }
    #pragma unroll
    for (int rnd = 0; rnd < 4; ++rnd){
      int o = rnd*256 + tid; int row = o >> 4; int cs = (o & 15)*8;
      __builtin_amdgcn_global_load_lds(GLD_SRC(vT + ((size_t)((b*NH + hh)*HD + row)*SS + k0 + cs)),
                                       GLD_DST(Vs + o*8), 16, 0, 0);
    }
    __syncthreads();    // drains vmcnt -> tiles ready

    // S = Q @ K^T  (16 q rows x 128 k cols per wave)
    f32x4 s[8] = {};
    #pragma unroll
    for (int kk = 0; kk < 2; ++kk){
      int kc = kk*32 + l4*8;
      short8 af = *(const short8*)&Qs[(wave*16 + l15)*64 + kc];
      #pragma unroll
      for (int n = 0; n < 8; ++n){
        short8 bf8 = *(const short8*)&Ks[(n*16 + l15)*64 + kc];
        s[n] = __builtin_amdgcn_mfma_f32_16x16x32_bf16(af, bf8, s[n], 0, 0, 0);
      }
    }

    bool diag = (kt == nkt - 1);
    #pragma unroll
    for (int j = 0; j < 4; ++j){
      int qg = q0 + wave*16 + l4*4 + j;
      float tmax = -1e30f;
      #pragma unroll
      for (int n = 0; n < 8; ++n){
        float v = s[n][j]*0.125f;
        if (diag && (k0 + n*16 + l15) > qg) v = -1e30f;
        s[n][j] = v; tmax = fmaxf(tmax, v);
      }
      tmax = fmaxf(tmax, __shfl_xor(tmax, 1, 64));
      tmax = fmaxf(tmax, __shfl_xor(tmax, 2, 64));
      tmax = fmaxf(tmax, __shfl_xor(tmax, 4, 64));
      tmax = fmaxf(tmax, __shfl_xor(tmax, 8, 64));
      float mnew = fmaxf(mrun[j], tmax);
      float alpha = __expf(mrun[j] - mnew);
      float rsum = 0.f;
      #pragma unroll
      for (int n = 0; n < 8; ++n){
        float p = __expf(s[n][j] - mnew);
        s[n][j] = p; rsum += p;
      }
      rsum += __shfl_xor(rsum, 1, 64);
      rsum += __shfl_xor(rsum, 2, 64);
      rsum += __shfl_xor(rsum, 4, 64);
      rsum += __shfl_xor(rsum, 8, 64);
      lrun[j] = lrun[j]*alpha + rsum;
      mrun[j] = mnew;
      #pragma unroll
      for (int n = 0; n < 4; ++n) acco[n][j] *= alpha;
      // write P row (bf16) to this wave's LDS region
      #pragma unroll
      for (int n = 0; n < 8; ++n){
        bf16 hv = __float2bfloat16(s[n][j]);
        Ps[wave][(l4*4 + j)*128 + n*16 + l15] = __builtin_bit_cast(short, hv);
      }
    }
    __syncthreads();   // order P writes before fragment reads (cheap, safe)

    // O += P @ V  (P: [16 q][128 k], V^T rows: [64 d][128 k])
    #pragma unroll
    for (int kk = 0; kk < 4; ++kk){
      int kc = kk*32 + l4*8;
      short8 pa = *(const short8*)&Ps[wave][l15*128 + kc];
      #pragma unroll
      for (int n = 0; n < 4; ++n){
        short8 vb = *(const short8*)&Vs[(n*16 + l15)*128 + kc];
        acco[n] = __builtin_amdgcn_mfma_f32_16x16x32_bf16(pa, vb, acco[n], 0, 0, 0);
      }
    }
  }

  #pragma unroll
  for (int j = 0; j < 4; ++j){
    float inv = 1.f / lrun[j];
    int qg = q0 + wave*16 + l4*4 + j;
    #pragma unroll
    for (int n = 0; n < 4; ++n){
      Ab[(size_t)(b*SS + qg)*E + hh*HD + n*16 + l15] = __float2bfloat16(acco[n][j]*inv);
    }
  }
}

// ---------------- seq-mean of h ----------------
__global__ __launch_bounds__(256) void hmean_kernel(const float* __restrict__ h, float* __restrict__ hm){
  int idx = blockIdx.x*256 + threadIdx.x;
  if (idx >= BB*E) return;
  int b = idx / E, e = idx % E;
  float s = 0.f;
  for (int t = 0; t < SS; ++t) s += h[((size_t)b*SS + t)*E + e];
  hm[idx] = s * (1.0f/SS);
}

// ---------------- gate = sigmoid(hm @ gW + gb) ----------------
__global__ __launch_bounds__(256) void gate_kernel(const float* __restrict__ hm, const float* __restrict__ gW,
                                                   const float* __restrict__ gb, float* __restrict__ gv){
  int idx = blockIdx.x*256 + threadIdx.x;
  if (idx >= BB*E) return;
  int b = idx / E, nn = idx % E;
  float acc = 0.f;
  for (int k = 0; k < E; ++k) acc += hm[b*E + k] * gW[(size_t)k*E + nn];
  acc += gb[nn];
  gv[idx] = 1.0f / (1.0f + __expf(-acc));
}

// ---------------- f32 -> bf16 activation convert ----------------
__global__ __launch_bounds__(256) void acvt_kernel(const float* __restrict__ A, bf16* __restrict__ Ab, int n4){
  int i = blockIdx.x*256 + threadIdx.x;
  if (i >= n4) return;
  float4 v = ((const float4*)A)[i];
  size_t b0 = (size_t)i*4;
  Ab[b0+0] = __float2bfloat16(v.x);
  Ab[b0+1] = __float2bfloat16(v.y);
  Ab[b0+2] = __float2bfloat16(v.z);
  Ab[b0+3] = __float2bfloat16(v.w);
}

// ---------------- W[K][N] f32 -> Wt[Npad][K] bf16 (transpose + convert, zero pad) ----------------
__global__ __launch_bounds__(256) void wcvt_kernel(const float* __restrict__ W, bf16* __restrict__ Wt,
                                                   int K, int N, int Npad){
  __shared__ float t[32][33];
  int n0 = blockIdx.x*32, k0 = blockIdx.y*32;
  int tx = threadIdx.x & 31, ty8 = threadIdx.x >> 5;
  #pragma unroll
  for (int i = 0; i < 4; ++i){
    int k = k0 + ty8 + i*8, n = n0 + tx;
    t[ty8 + i*8][tx] = (k < K && n < N) ? W[(size_t)k*N + n] : 0.f;
  }
  __syncthreads();
  #pragma unroll
  for (int i = 0; i < 4; ++i){
    int n = n0 + ty8 + i*8, k = k0 + tx;
    if (n < Npad && k < K) Wt[(size_t)n*K + k] = __float2bfloat16(t[tx][ty8 + i*8]);
  }
}

// ---------------- MFMA GEMM: C[M,N](f32) = A[M,K](bf16) @ Wt[Npad,K]^T (+bias) (+gelu) ----------------
template<int EPI>
__global__ __launch_bounds__(256) void mfma_gemm(const bf16* __restrict__ A, const bf16* __restrict__ Bt,
                                                 const float* __restrict__ bias, float* __restrict__ C,
                                                 int M, int N, int K){
  __shared__ short As[128*64];
  __shared__ short Bs[128*64];
  int tid = threadIdx.x;
  int wave = tid >> 6, lane = tid & 63;
  int wr = wave >> 1, wc = wave & 1;
  int m0 = blockIdx.y * 128, n0 = blockIdx.x * 128;
  f32x4 acc[4][4] = {};
  int srow = tid >> 3;
  int scol = (tid & 7) * 8;
  const int nks = K >> 6;
  for (int kt = 0; kt < nks; ++kt){
    int kbase = kt * 64;
    __syncthreads();
    #pragma unroll
    for (int iss = 0; iss < 4; ++iss){
      int r = srow + iss*32;
      __builtin_amdgcn_global_load_lds(GLD_SRC(A + (size_t)(m0 + r)*K + kbase + scol),
                                       GLD_DST(As + r*64 + scol), 16, 0, 0);
      __builtin_amdgcn_global_load_lds(GLD_SRC(Bt + (size_t)(n0 + r)*K + kbase + scol),
                                       GLD_DST(Bs + r*64 + scol), 16, 0, 0);
    }
    __syncthreads();
    #pragma unroll
    for (int kk = 0; kk < 2; ++kk){
      short8 af[4], bfr[4];
      int kcol = kk*32 + (lane >> 4)*8;
      #pragma unroll
      for (int m = 0; m < 4; ++m)
        af[m] = *(const short8*)&As[(wr*64 + m*16 + (lane & 15))*64 + kcol];
      #pragma unroll
      for (int n = 0; n < 4; ++n)
        bfr[n] = *(const short8*)&Bs[(wc*64 + n*16 + (lane & 15))*64 + kcol];
      #pragma unroll
      for (int m = 0; m < 4; ++m)
        #pragma unroll
        for (int n = 0; n < 4; ++n)
          acc[m][n] = __builtin_amdgcn_mfma_f32_16x16x32_bf16(af[m], bfr[n], acc[m][n], 0, 0, 0);
    }
  }
  int lrow = (lane >> 4)*4, lcol = lane & 15;
  #pragma unroll
  for (int m = 0; m < 4; ++m){
    int row = m0 + wr*64 + m*16 + lrow;
    #pragma unroll
    for (int n = 0; n < 4; ++n){
      int col = n0 + wc*64 + n*16 + lcol;
      if (col >= N) continue;
      float bv = 0.f;
      if (EPI != 2) bv = bias[col];
      #pragma unroll
      for (int j = 0; j < 4; ++j){
        float v = acc[m][n][j] + bv;
        if (EPI == 1) v = 0.5f*v*(1.0f + erff(v*0.70710678f));
        C[(size_t)(row + j)*N + col] = v;
      }
    }
  }
}

// ---------------- residual (+gate) + layernorm ----------------
__global__ __launch_bounds__(256) void ln_kernel(const float* __restrict__ a, const float* __restrict__ resid,
                                                 const float* __restrict__ gatev, const float* __restrict__ g,
                                                 const float* __restrict__ bta, float* __restrict__ out){
  int row = blockIdx.x;
  int b = row >> 10;
  int tid = threadIdx.x;
  __shared__ float sred[4];
  float y[3];
  float lsum = 0.f;
  #pragma unroll
  for (int i = 0; i < 3; ++i){
    int e = tid + i*256;
    float v = a[(size_t)row*E + e];
    if (gatev) v *= gatev[b*E + e];
    if (resid) v += resid[(size_t)row*E + e];
    y[i] = v; lsum += v;
  }
  for (int off = 32; off > 0; off >>= 1) lsum += __shfl_down(lsum, off, 64);
  int wid = tid >> 6, lane = tid & 63;
  if (lane == 0) sred[wid] = lsum;
  __syncthreads();
  float mean = (sred[0]+sred[1]+sred[2]+sred[3]) * (1.0f/E);
  __syncthreads();
  float lvar = 0.f;
  #pragma unroll
  for (int i = 0; i < 3; ++i){ float d = y[i]-mean; lvar += d*d; }
  for (int off = 32; off > 0; off >>= 1) lvar += __shfl_down(lvar, off, 64);
  if (lane == 0) sred[wid] = lvar;
  __syncthreads();
  float rstd = rsqrtf((sred[0]+sred[1]+sred[2]+sred[3]) * (1.0f/E) + EPSL);
  __syncthreads();
  #pragma unroll
  for (int i = 0; i < 3; ++i){
    int e = tid + i*256;
    out[(size_t)row*E + e] = (y[i]-mean)*rstd*g[e] + bta[e];
  }
}

extern "C" void kernel_launch(void* const* d_in, const int* in_sizes, int n_in,
                              void* d_out, int out_size, void* d_ws, size_t ws_size,
                              hipStream_t stream) {
  const int*   x      = (const int*)  d_in[0];
  const float* embedW = (const float*)d_in[2];
  const float* pos    = (const float*)d_in[3];
  const float* fcW    = (const float*)d_in[4];
  const float* fcB    = (const float*)d_in[5];
  const float* gW     = (const float*)d_in[6];
  const float* gB     = (const float*)d_in[7];
  const float* ln1g   = (const float*)d_in[8];
  const float* ln1b   = (const float*)d_in[9];
  const float* ln2g   = (const float*)d_in[10];
  const float* ln2b   = (const float*)d_in[11];
  const float* f1W    = (const float*)d_in[12];
  const float* f1B    = (const float*)d_in[13];
  const float* f2W    = (const float*)d_in[14];
  const float* f2B    = (const float*)d_in[15];
  const float* lnfg   = (const float*)d_in[16];
  const float* lnfb   = (const float*)d_in[17];
  const float* headW  = (const float*)d_in[18];
  float* out = (float*)d_out;

  const size_t BSE = (size_t)BB*SS*E;
  float* h   = (float*)d_ws;
  float* o   = h   + BSE;        // reused: hb + vT (bf16) live here
  float* tmp = o   + BSE;
  float* f1  = tmp + BSE;
  float* hm  = f1  + BSE*FEE;
  float* gv  = hm  + (size_t)BB*E;
  bf16* Abuf   = (bf16*)(gv + (size_t)BB*E);
  bf16* Wbuf   = Abuf + (size_t)2048*3072;
  bf16* WheadT = Wbuf + (size_t)3072*768;
  bf16* hb     = (bf16*)o;                 // [2048][768]
  bf16* vT     = hb + BSE;                 // [B*NH*HD][SS]

  const int rows = BB*SS;   // 2048

  embed_kernel<<<(int)((BSE + 255)/256), 256, 0, stream>>>(x, embedW, pos, h);

  // head weight: f32 [E][V] -> bf16 [NPADH][E] once
  {
    dim3 g(NPADH/32, E/32);
    wcvt_kernel<<<g, 256, 0, stream>>>(headW, WheadT, E, V, NPADH);
  }

  for (int l = 0; l < NL; ++l){
    size_t oEE = (size_t)l*E*E, oE = (size_t)l*E;
    size_t oF1 = (size_t)l*E*FEE*E, oFb = (size_t)l*FEE*E;

    hmean_kernel<<<(BB*E + 255)/256, 256, 0, stream>>>(h, hm);
    gate_kernel<<<(BB*E + 255)/256, 256, 0, stream>>>(hm, gW + oEE, gB + oE, gv);

    cvt_attn<<<BB*NH*16, 256, 0, stream>>>(h, hb, vT);
    attn_mfma<<<BB*NH*16, 256, 0, stream>>>(hb, vT, Abuf);

    // fc_out: (2048x768) @ (768x768)
    { dim3 g(E/32, E/32);  wcvt_kernel<<<g, 256, 0, stream>>>(fcW + oEE, Wbuf, E, E, E); }
    { dim3 g(E/128, rows/128);
      mfma_gemm<0><<<g, 256, 0, stream>>>(Abuf, Wbuf, fcB + oE, tmp, rows, E, E); }

    ln_kernel<<<rows, 256, 0, stream>>>(tmp, h, gv, ln1g + oE, ln1b + oE, h);

    // ff1: (2048x768) @ (768x3072) + gelu
    acvt_kernel<<<(int)(BSE/4 + 255)/256, 256, 0, stream>>>(h, Abuf, (int)(BSE/4));
    { dim3 g((FEE*E)/32, E/32); wcvt_kernel<<<g, 256, 0, stream>>>(f1W + oF1, Wbuf, E, FEE*E, FEE*E); }
    { dim3 g((FEE*E)/128, rows/128);
      mfma_gemm<1><<<g, 256, 0, stream>>>(Abuf, Wbuf, f1B + oFb, f1, rows, FEE*E, E); }

    // ff2: (2048x3072) @ (3072x768)
    acvt_kernel<<<(int)(BSE*FEE/4 + 255)/256, 256, 0, stream>>>(f1, Abuf, (int)(BSE*FEE/4));
    { dim3 g(E/32, (FEE*E)/32); wcvt_kernel<<<g, 256, 0, stream>>>(f2W + oF1, Wbuf, FEE*E, E, E); }
    { dim3 g(E/128, rows/128);
      mfma_gemm<0><<<g, 256, 0, stream>>>(Abuf, Wbuf, f2B + oE, tmp, rows, E, FEE*E); }

    ln_kernel<<<rows, 256, 0, stream>>>(tmp, h, nullptr, ln2g + oE, ln2b + oE, h);
  }

  ln_kernel<<<rows, 256, 0, stream>>>(h, nullptr, nullptr, lnfg, lnfb, tmp);
  acvt_kernel<<<(int)(BSE/4 + 255)/256, 256, 0, stream>>>(tmp, Abuf, (int)(BSE/4));
  {
    dim3 g(NPADH/128, rows/128);
    mfma_gemm<2><<<g, 256, 0, stream>>>(Abuf, WheadT, nullptr, out, rows, V, E);
  }
}